// Round 13
// baseline (137.741 us; speedup 1.0000x reference)
//
#include <hip/hip_runtime.h>
#include <hip/hip_bf16.h>

// ---------------- problem constants ----------------
#define T_STEPS 16
#define BATCH   64
#define M_ROWS  1024          // T*B
#define K_DIM   60000
#define N1      200
#define N2      50
#define N3      2
#define NPAD    256           // w1b rows allocated (200..255 junk: feed only unstored acc cols)
#define HN      (M_ROWS * N1) // 204800 elems per [m][n] slab
#define BK      32            // k per step

typedef __attribute__((ext_vector_type(8)))  short bf16x8;
typedef __attribute__((ext_vector_type(16))) float f32x16;

// pack 8 f32 -> 8 bf16 (compiler emits v_cvt_pk_bf16_f32)
static __device__ __forceinline__ bf16x8 cvt8(float4 lo, float4 hi) {
    union { bf16x8 v; __hip_bfloat162 h[4]; } u;
    u.h[0] = __float22bfloat162_rn(make_float2(lo.x, lo.y));
    u.h[1] = __float22bfloat162_rn(make_float2(lo.z, lo.w));
    u.h[2] = __float22bfloat162_rn(make_float2(hi.x, hi.y));
    u.h[3] = __float22bfloat162_rn(make_float2(hi.z, hi.w));
    return u.v;
}

static __device__ __forceinline__ float bf2f(unsigned short u) {
    unsigned int x = (unsigned int)u << 16;
    return __uint_as_float(x);
}

// async global->LDS, 16B per lane (dest = wave-uniform base + lane*16)
typedef __attribute__((address_space(3))) unsigned int       lds_u32;
typedef __attribute__((address_space(1))) const unsigned int glb_u32;
static __device__ __forceinline__ void gll16(const void* g, void* l) {
    __builtin_amdgcn_global_load_lds((glb_u32*)(unsigned long long)g,
                                     (lds_u32*)(unsigned int)(unsigned long long)l,
                                     16, 0, 0);
}

// Kernel 0: W1 f32 -> bf16 (rows < 200 only).
__global__ __launch_bounds__(256)
void cvt_w1(const float* __restrict__ w1, unsigned short* __restrict__ w1b) {
    const size_t e = ((size_t)blockIdx.x * 256 + threadIdx.x) * 8;
    if (e >= (size_t)N1 * K_DIM) return;
    *(bf16x8*)(w1b + e) = cvt8(*(const float4*)(w1 + e),
                               *(const float4*)(w1 + e + 4));
}

// Kernel 1: part[s] = X[:, seg_s] @ W1b[:, seg_s].T   (bf16 partials out)
// r12 structure (128m x 256n, BK=32, 8 waves 2x4, 32x32x16 MFMA, 2-deep
// counted-vmcnt pipeline, granule-XOR swizzle, 2 blocks/CU).
// This round: KSPLIT 75 (25 steps, 600 blocks) + T5 s_setprio around the
// MFMA cluster (2 co-resident blocks at different steps give the scheduler
// role diversity to arbitrate).
template <int KSEG, int KSTEPS, int NWG>
__global__ __launch_bounds__(512, 4)
void gemm_lds(const float* __restrict__ x,
              const unsigned short* __restrict__ w1b,
              unsigned short* __restrict__ part) {
    __shared__ __align__(16) char smem[2][24576];   // [A 8KB][B 16KB] per buf

    const int tid = threadIdx.x;
    const int l   = tid & 63;
    const int wv  = tid >> 6;          // 0..7
    const int wm  = wv & 1;            // wave m index (2)
    const int wn  = wv >> 1;           // wave n index (4)

    // bijective XCD-chunked swizzle (NWG % 8 == 0): the 8 blocks sharing a
    // k-segment are logically consecutive -> land on one XCD's L2.
    const int hw      = blockIdx.y * 8 + blockIdx.x;
    const int logical = (hw & 7) * (NWG / 8) + (hw >> 3);
    const int s  = logical >> 3;
    const int mt = logical & 7;

    const int m0 = mt * 128;
    const int k0 = s * KSEG;

    // A staging: f32 global -> regs -> cvt_pk -> swizzled ds_write.
    const int ar = tid >> 2;            // 0..127 row
    const int ag = tid & 3;             // 8-float granule
    const float* asrc = x + (size_t)(m0 + ar) * K_DIM + k0 + ag * 8;
    const int aw_off = ar * 64 + ((ag ^ ((ar >> 1) & 3)) << 4);   // swizzled

    // B staging via gll16: 16 chunks of 1KB; wave wv -> chunks wv*2, wv*2+1.
    // Linear LDS dest; SOURCE granule pre-swizzled with the same involution.
    const char* bsrc[2];
    int bl_off[2];
    #pragma unroll
    for (int j = 0; j < 2; ++j) {
        const int c   = wv * 2 + j;
        const int row = c * 16 + (l >> 2);
        bl_off[j] = 8192 + c * 1024 + l * 16;       // linear [row][64B]
        bsrc[j]   = (const char*)(w1b + (size_t)row * K_DIM + k0)
                    + (((l & 3) ^ ((row >> 1) & 3)) << 4);        // pre-swizzled
    }

    f32x16 acc[2][2];
    #pragma unroll
    for (int i = 0; i < 2; ++i)
        #pragma unroll
        for (int j = 0; j < 2; ++j)
            #pragma unroll
            for (int q = 0; q < 16; ++q) acc[i][j][q] = 0.f;

    // ---- prologue: B(0) gll16 first, then A(0), A(1) reg loads ----
    float4 pA[2][2];                    // [step-parity slot][2 x float4]
    gll16(bsrc[0], smem[0] + bl_off[0]);
    gll16(bsrc[1], smem[0] + bl_off[1]);
    pA[0][0] = *(const float4*)asrc;
    pA[0][1] = *(const float4*)(asrc + 4);
    pA[1][0] = *(const float4*)(asrc + BK);
    pA[1][1] = *(const float4*)(asrc + BK + 4);
    *(bf16x8*)(smem[0] + aw_off) = cvt8(pA[0][0], pA[0][1]);
    __builtin_amdgcn_sched_barrier(0);
    asm volatile("s_waitcnt vmcnt(2)" ::: "memory");   // B(0) done; A(1) may fly
    __syncthreads();

    const int fr = l & 31;              // fragment row/col
    const int fh = (l >> 5) * 16;       // 16B half within 32B k-chunk

    #pragma unroll 2
    for (int it = 0; it < KSTEPS; ++it) {
        const int cur = it & 1;
        const bool more = (it + 1) < KSTEPS;

        // phase 1: issue B(it+1) gll16 (first), then A(it+2) reg loads
        if (more) {
            gll16(bsrc[0] + (size_t)(it + 1) * (BK * 2), smem[cur ^ 1] + bl_off[0]);
            gll16(bsrc[1] + (size_t)(it + 1) * (BK * 2), smem[cur ^ 1] + bl_off[1]);
            const int jn = (it + 2 < KSTEPS) ? (it + 2) : (KSTEPS - 1);
            pA[cur][0] = *(const float4*)(asrc + jn * BK);     // slot (it+2)&1 == cur
            pA[cur][1] = *(const float4*)(asrc + jn * BK + 4);
        }
        __builtin_amdgcn_sched_barrier(0);

        // phase 2: 8 swizzled ds_read + 8 MFMA (32x32x16), T5 setprio wrap
        const char* ab = smem[cur];
        const char* bb = smem[cur] + 8192;
        __builtin_amdgcn_s_setprio(1);
        #pragma unroll
        for (int kk = 0; kk < 2; ++kk) {
            const int r0 = wm * 64 + fr;
            const int r1 = wm * 64 + 32 + fr;
            bf16x8 a0 = *(const bf16x8*)(ab + r0 * 64 + ((kk * 32 + fh) ^ (((r0 >> 1) & 3) << 4)));
            bf16x8 a1 = *(const bf16x8*)(ab + r1 * 64 + ((kk * 32 + fh) ^ (((r1 >> 1) & 3) << 4)));
            #pragma unroll
            for (int fn = 0; fn < 2; ++fn) {
                const int n = wn * 64 + fn * 32 + fr;
                bf16x8 bv = *(const bf16x8*)(bb + n * 64 + ((kk * 32 + fh) ^ (((n >> 1) & 3) << 4)));
                acc[0][fn] = __builtin_amdgcn_mfma_f32_32x32x16_bf16(a0, bv, acc[0][fn], 0, 0, 0);
                acc[1][fn] = __builtin_amdgcn_mfma_f32_32x32x16_bf16(a1, bv, acc[1][fn], 0, 0, 0);
            }
        }
        __builtin_amdgcn_s_setprio(0);

        // phase 3: cvt A(it+1) (slot cur^1) -> swizzled ds_write into buf^1
        if (more) {
            *(bf16x8*)(smem[cur ^ 1] + aw_off) = cvt8(pA[cur ^ 1][0], pA[cur ^ 1][1]);
            __builtin_amdgcn_sched_barrier(0);
            asm volatile("s_waitcnt vmcnt(2)" ::: "memory");   // B(it+1) landed
            __syncthreads();
        }
    }

    // epilogue: store cols < 200 as bf16, part layout [s][m][n], ld = 200
    // C/D layout (m74/m101): col = l&31, row = (reg&3) + 8*(reg>>2) + 4*(l>>5)
    const int col = l & 31;
    const int rhi = (l >> 5) * 4;
    #pragma unroll
    for (int fm = 0; fm < 2; ++fm)
        #pragma unroll
        for (int fn = 0; fn < 2; ++fn) {
            const int gn = wn * 64 + fn * 32 + col;
            if (gn < N1) {
                const int gmb = m0 + wm * 64 + fm * 32 + rhi;
                #pragma unroll
                for (int r = 0; r < 16; ++r) {
                    const int gm = gmb + (r & 3) + 8 * (r >> 2);
                    __hip_bfloat16 hv = __float2bfloat16(acc[fm][fn][r]);
                    part[(size_t)s * HN + (size_t)gm * N1 + gn] = *(unsigned short*)&hv;
                }
            }
        }
}

// Kernel 2: dense deterministic s-reduction of bf16 partials -> f32 h1.
template <int KSPLIT>
__global__ __launch_bounds__(256)
void reduce_kernel(const unsigned short* __restrict__ part, float* __restrict__ h1) {
    const size_t f = ((size_t)blockIdx.x * 256 + threadIdx.x) * 2;   // < 204800
    float a0 = 0.f, a1 = 0.f;
    #pragma unroll 15
    for (int s = 0; s < KSPLIT; ++s) {
        const unsigned int v = *(const unsigned int*)(part + (size_t)s * HN + f);
        a0 += bf2f((unsigned short)(v & 0xFFFFu));
        a1 += bf2f((unsigned short)(v >> 16));
    }
    h1[f]     = a0;
    h1[f + 1] = a1;
}

// Kernel 3: fused LIF tail, latency-tolerant. One block per batch b.
__global__ __launch_bounds__(256)
void tail_kernel(const float* __restrict__ h1,
                 const float* __restrict__ w2, const float* __restrict__ w3,
                 float* __restrict__ out) {
    __shared__ float w2s[N2 * N1];                  // 40 KB
    __shared__ float w3s[N3 * N2];
    __shared__ unsigned long long msk[T_STEPS][4];

    const int b    = blockIdx.x;
    const int i    = threadIdx.x;
    const int wv   = i >> 6;
    const int lane = i & 63;

    for (int o = i; o < (N2 * N1) / 4; o += 256)
        ((float4*)w2s)[o] = ((const float4*)w2)[o];
    if (i < N3 * N2) w3s[i] = w3[i];

    float h[T_STEPS];
    #pragma unroll
    for (int t = 0; t < T_STEPS; ++t)
        h[t] = (i < N1) ? h1[(size_t)(t * BATCH + b) * N1 + i] : 0.f;

    float v1 = 0.f;
    #pragma unroll
    for (int t = 0; t < T_STEPS; ++t) {
        v1 += (h[t] - v1) * 0.5f;
        bool sp = (v1 - 1.0f) >= 0.f;
        unsigned long long m = __ballot(sp);
        if (sp) v1 = 0.f;
        if (lane == 0) msk[t][wv] = m;
    }
    __syncthreads();

    if (wv == 0) {
        float v2 = 0.f, v3 = 0.f;
        for (int t = 0; t < T_STEPS; ++t) {
            float h2 = 0.f;
            if (lane < N2) {
                #pragma unroll
                for (int w = 0; w < 4; ++w) {
                    unsigned long long m = msk[t][w];
                    while (m) {
                        int lz = __builtin_ctzll(m);
                        m &= m - 1;
                        h2 += w2s[lane * N1 + (w * 64 + lz)];
                    }
                }
            }
            v2 += (h2 - v2) * 0.5f;
            bool sp2 = (v2 - 1.0f) >= 0.f;
            unsigned long long bal2 = __ballot(sp2);
            if (sp2) v2 = 0.f;

            float h3 = 0.f;
            if (lane < N3) {
                unsigned long long m = bal2;
                while (m) {
                    int j = __builtin_ctzll(m);
                    m &= m - 1;
                    h3 += w3s[lane * N2 + j];
                }
            }
            v3 += (h3 - v3) * 0.5f;
            bool sp3 = (v3 - 1.0f) >= 0.f;
            if (lane < N3)
                out[(size_t)(t * BATCH + b) * N3 + lane] = sp3 ? 1.f : 0.f;
            if (sp3) v3 = 0.f;
        }
    }
}

extern "C" void kernel_launch(void* const* d_in, const int* in_sizes, int n_in,
                              void* d_out, int out_size, void* d_ws, size_t ws_size,
                              hipStream_t stream) {
    const float* x  = (const float*)d_in[0];   // [16,64,150,400] -> [1024][60000]
    const float* w1 = (const float*)d_in[1];   // [200][60000]
    const float* w2 = (const float*)d_in[2];   // [50][200]
    const float* w3 = (const float*)d_in[3];   // [2][50]
    float* out = (float*)d_out;                // [16][64][2]

    // ws layout: part bf16 [KSPLIT][1024][200], h1 f32, w1b bf16 [256][60000]
    const size_t w1b_bytes = (size_t)NPAD * K_DIM * 2;                 // 30.72 MB
    const size_t h1_bytes  = (size_t)HN * 4;                           // 0.82 MB
    const size_t need75 = (size_t)75 * HN * 2 + h1_bytes + w1b_bytes;  // ~62.3 MB
    const bool big = ws_size >= need75;

    const int ksplit = big ? 75 : 25;
    unsigned short* part = (unsigned short*)d_ws;
    float* h1 = (float*)((char*)d_ws + (size_t)ksplit * HN * 2);
    unsigned short* w1b = (unsigned short*)((char*)h1 + h1_bytes);

    cvt_w1<<<(N1 * K_DIM / 8 + 255) / 256, 256, 0, stream>>>(w1, w1b);
    if (big) {
        dim3 g(8, 75);
        gemm_lds<800, 25, 600><<<g, 512, 0, stream>>>(x, w1b, part);
        reduce_kernel<75><<<HN / 512, 256, 0, stream>>>(part, h1);
    } else {
        dim3 g(8, 25);
        gemm_lds<2400, 75, 200><<<g, 512, 0, stream>>>(x, w1b, part);
        reduce_kernel<25><<<HN / 512, 256, 0, stream>>>(part, h1);
    }
    tail_kernel<<<BATCH, 256, 0, stream>>>(h1, w2, w3, out);
}

// Round 14
// 102.032 us; speedup vs baseline: 1.3500x; 1.3500x over previous
//
#include <hip/hip_runtime.h>
#include <hip/hip_bf16.h>

// ---------------- problem constants ----------------
#define T_STEPS 16
#define BATCH   64
#define M_ROWS  1024          // T*B
#define K_DIM   60000
#define N1      200
#define N2      50
#define N3      2
#define HN      (M_ROWS * N1) // 204800 elems per [m][n] slab
#define BK      32            // k per step

typedef __attribute__((ext_vector_type(8)))  short bf16x8;
typedef __attribute__((ext_vector_type(16))) float f32x16;

// pack 8 f32 -> 8 bf16 (compiler emits v_cvt_pk_bf16_f32)
static __device__ __forceinline__ bf16x8 cvt8(float4 lo, float4 hi) {
    union { bf16x8 v; __hip_bfloat162 h[4]; } u;
    u.h[0] = __float22bfloat162_rn(make_float2(lo.x, lo.y));
    u.h[1] = __float22bfloat162_rn(make_float2(lo.z, lo.w));
    u.h[2] = __float22bfloat162_rn(make_float2(hi.x, hi.y));
    u.h[3] = __float22bfloat162_rn(make_float2(hi.z, hi.w));
    return u.v;
}

static __device__ __forceinline__ float bf2f(unsigned short u) {
    unsigned int x = (unsigned int)u << 16;
    return __uint_as_float(x);
}

// Kernel 1: part[s] = X[:, seg_s] @ W1[:, seg_s].T   (bf16 partials out)
// r12 compute structure (128m x 256n, BK=32, 8 waves 2x4, 32x32x16 MFMA,
// granule-XOR swizzle g' = g ^ ((row>>1)&3), 2 blocks/CU), but BOTH operands
// reg-staged straight from f32 (W1 read directly -- no w1b pre-convert
// kernel, no gll16/vmcnt machinery; HBM -72 MB vs r12, one fewer kernel).
// The 8 blocks sharing a k-segment are XCD-grouped; a W1 f32 segment
// (491 KB) fits that XCD's L2, so 7/8 of B reads are L2 hits.
//   per step: ph1 issue B(it+1)+A(it+2) reg loads | SBAR |
//             ph2 8 swizzled ds_read + 8 MFMA      |
//             ph3 cvt+swizzled ds_write A(it+1),B(it+1) -> buf^1 | SBAR | bar
template <int KSEG, int KSTEPS, int NWG>
__global__ __launch_bounds__(512, 4)
void gemm_lds(const float* __restrict__ x,
              const float* __restrict__ w1,
              unsigned short* __restrict__ part) {
    __shared__ __align__(16) char smem[2][24576];   // [A 8KB][B 16KB] per buf

    const int tid = threadIdx.x;
    const int l   = tid & 63;
    const int wv  = tid >> 6;          // 0..7
    const int wm  = wv & 1;            // wave m index (2)
    const int wn  = wv >> 1;           // wave n index (4)

    // bijective XCD-chunked swizzle (NWG % 8 == 0): the 8 blocks sharing a
    // k-segment are logically consecutive -> land on one XCD's L2.
    const int hw      = blockIdx.y * 8 + blockIdx.x;
    const int logical = (hw & 7) * (NWG / 8) + (hw >> 3);
    const int s  = logical >> 3;
    const int mt = logical & 7;

    const int m0 = mt * 128;
    const int k0 = s * KSEG;

    // A staging: thread -> (row ar = tid>>2, 8-f32 granule ag = tid&3)
    const int ar = tid >> 2;            // 0..127
    const int ag = tid & 3;
    const float* asrc = x + (size_t)(m0 + ar) * K_DIM + k0 + ag * 8;
    const int aw_off = ar * 64 + ((ag ^ ((ar >> 1) & 3)) << 4);   // swizzled

    // B staging: thread -> (row br = tid>>1, 16-f32 half bh = tid&1)
    const int br = tid >> 1;            // 0..255 (B/W1 row)
    const int bh = tid & 1;
    const bool bvalid = br < N1;        // rows 200..255: never load (OOB);
                                        // junk LDS feeds only unstored cols
    const float* bsrc = w1 + (size_t)br * K_DIM + k0 + bh * 16;
    const int bg0 = bh * 2;             // first of two 8-elem granules
    const int bw_off0 = 8192 + br * 64 + (((bg0)     ^ ((br >> 1) & 3)) << 4);
    const int bw_off1 = 8192 + br * 64 + (((bg0 + 1) ^ ((br >> 1) & 3)) << 4);

    f32x16 acc[2][2];
    #pragma unroll
    for (int i = 0; i < 2; ++i)
        #pragma unroll
        for (int j = 0; j < 2; ++j)
            #pragma unroll
            for (int q = 0; q < 16; ++q) acc[i][j][q] = 0.f;

    float4 pA[2][2];                    // A reg slots, [step parity][2]
    float4 pB[4];                       // B(next) 16 f32
    #pragma unroll
    for (int j = 0; j < 4; ++j) pB[j] = (float4){0.f, 0.f, 0.f, 0.f};

    // ---- prologue: stage step 0; preload A(1) regs ----
    pA[0][0] = *(const float4*)asrc;
    pA[0][1] = *(const float4*)(asrc + 4);
    if (bvalid) {
        pB[0] = *(const float4*)bsrc;
        pB[1] = *(const float4*)(bsrc + 4);
        pB[2] = *(const float4*)(bsrc + 8);
        pB[3] = *(const float4*)(bsrc + 12);
    }
    pA[1][0] = *(const float4*)(asrc + BK);
    pA[1][1] = *(const float4*)(asrc + BK + 4);
    *(bf16x8*)(smem[0] + aw_off) = cvt8(pA[0][0], pA[0][1]);
    *(bf16x8*)(smem[0] + bw_off0) = cvt8(pB[0], pB[1]);
    *(bf16x8*)(smem[0] + bw_off1) = cvt8(pB[2], pB[3]);
    __syncthreads();

    const int fr = l & 31;              // fragment row/col
    const int fh = (l >> 5) * 16;       // 16B half within 32B k-chunk

    #pragma unroll
    for (int it = 0; it < KSTEPS; ++it) {
        const int cur = it & 1;
        const bool more = (it + 1) < KSTEPS;

        // phase 1: issue B(it+1) and A(it+2) register loads
        if (more) {
            if (bvalid) {
                const float* bp = bsrc + (size_t)(it + 1) * BK;
                pB[0] = *(const float4*)bp;
                pB[1] = *(const float4*)(bp + 4);
                pB[2] = *(const float4*)(bp + 8);
                pB[3] = *(const float4*)(bp + 12);
            }
            const int jn = (it + 2 < KSTEPS) ? (it + 2) : (KSTEPS - 1);
            pA[cur][0] = *(const float4*)(asrc + jn * BK);   // slot (it+2)&1 == cur
            pA[cur][1] = *(const float4*)(asrc + jn * BK + 4);
        }
        __builtin_amdgcn_sched_barrier(0);

        // phase 2: 8 swizzled ds_read + 8 MFMA (32x32x16) on buf[cur]
        const char* ab = smem[cur];
        const char* bb = smem[cur] + 8192;
        #pragma unroll
        for (int kk = 0; kk < 2; ++kk) {
            const int r0 = wm * 64 + fr;
            const int r1 = wm * 64 + 32 + fr;
            bf16x8 a0 = *(const bf16x8*)(ab + r0 * 64 + ((kk * 32 + fh) ^ (((r0 >> 1) & 3) << 4)));
            bf16x8 a1 = *(const bf16x8*)(ab + r1 * 64 + ((kk * 32 + fh) ^ (((r1 >> 1) & 3) << 4)));
            #pragma unroll
            for (int fn = 0; fn < 2; ++fn) {
                const int n = wn * 64 + fn * 32 + fr;
                bf16x8 bv = *(const bf16x8*)(bb + n * 64 + ((kk * 32 + fh) ^ (((n >> 1) & 3) << 4)));
                acc[0][fn] = __builtin_amdgcn_mfma_f32_32x32x16_bf16(a0, bv, acc[0][fn], 0, 0, 0);
                acc[1][fn] = __builtin_amdgcn_mfma_f32_32x32x16_bf16(a1, bv, acc[1][fn], 0, 0, 0);
            }
        }

        // phase 3: cvt + swizzled ds_write of A(it+1), B(it+1) into buf^1
        if (more) {
            char* nb = smem[cur ^ 1];
            *(bf16x8*)(nb + aw_off)  = cvt8(pA[cur ^ 1][0], pA[cur ^ 1][1]);
            *(bf16x8*)(nb + bw_off0) = cvt8(pB[0], pB[1]);
            *(bf16x8*)(nb + bw_off1) = cvt8(pB[2], pB[3]);
            __builtin_amdgcn_sched_barrier(0);
            __syncthreads();
        }
    }

    // epilogue: store cols < 200 as bf16, part layout [s][m][n], ld = 200
    // C/D layout (m74/m101): col = l&31, row = (reg&3) + 8*(reg>>2) + 4*(l>>5)
    const int col = l & 31;
    const int rhi = (l >> 5) * 4;
    #pragma unroll
    for (int fm = 0; fm < 2; ++fm)
        #pragma unroll
        for (int fn = 0; fn < 2; ++fn) {
            const int gn = wn * 64 + fn * 32 + col;
            if (gn < N1) {
                const int gmb = m0 + wm * 64 + fm * 32 + rhi;
                #pragma unroll
                for (int r = 0; r < 16; ++r) {
                    const int gm = gmb + (r & 3) + 8 * (r >> 2);
                    __hip_bfloat16 hv = __float2bfloat16(acc[fm][fn][r]);
                    part[(size_t)s * HN + (size_t)gm * N1 + gn] = *(unsigned short*)&hv;
                }
            }
        }
}

// Kernel 2: dense deterministic s-reduction of bf16 partials -> f32 h1.
template <int KSPLIT>
__global__ __launch_bounds__(256)
void reduce_kernel(const unsigned short* __restrict__ part, float* __restrict__ h1) {
    const size_t f = ((size_t)blockIdx.x * 256 + threadIdx.x) * 2;   // < 204800
    float a0 = 0.f, a1 = 0.f;
    #pragma unroll 25
    for (int s = 0; s < KSPLIT; ++s) {
        const unsigned int v = *(const unsigned int*)(part + (size_t)s * HN + f);
        a0 += bf2f((unsigned short)(v & 0xFFFFu));
        a1 += bf2f((unsigned short)(v >> 16));
    }
    h1[f]     = a0;
    h1[f + 1] = a1;
}

// Kernel 3: fused LIF tail, latency-tolerant. One block per batch b.
__global__ __launch_bounds__(256)
void tail_kernel(const float* __restrict__ h1,
                 const float* __restrict__ w2, const float* __restrict__ w3,
                 float* __restrict__ out) {
    __shared__ float w2s[N2 * N1];                  // 40 KB
    __shared__ float w3s[N3 * N2];
    __shared__ unsigned long long msk[T_STEPS][4];

    const int b    = blockIdx.x;
    const int i    = threadIdx.x;
    const int wv   = i >> 6;
    const int lane = i & 63;

    for (int o = i; o < (N2 * N1) / 4; o += 256)
        ((float4*)w2s)[o] = ((const float4*)w2)[o];
    if (i < N3 * N2) w3s[i] = w3[i];

    float h[T_STEPS];
    #pragma unroll
    for (int t = 0; t < T_STEPS; ++t)
        h[t] = (i < N1) ? h1[(size_t)(t * BATCH + b) * N1 + i] : 0.f;

    float v1 = 0.f;
    #pragma unroll
    for (int t = 0; t < T_STEPS; ++t) {
        v1 += (h[t] - v1) * 0.5f;
        bool sp = (v1 - 1.0f) >= 0.f;
        unsigned long long m = __ballot(sp);
        if (sp) v1 = 0.f;
        if (lane == 0) msk[t][wv] = m;
    }
    __syncthreads();

    if (wv == 0) {
        float v2 = 0.f, v3 = 0.f;
        for (int t = 0; t < T_STEPS; ++t) {
            float h2 = 0.f;
            if (lane < N2) {
                #pragma unroll
                for (int w = 0; w < 4; ++w) {
                    unsigned long long m = msk[t][w];
                    while (m) {
                        int lz = __builtin_ctzll(m);
                        m &= m - 1;
                        h2 += w2s[lane * N1 + (w * 64 + lz)];
                    }
                }
            }
            v2 += (h2 - v2) * 0.5f;
            bool sp2 = (v2 - 1.0f) >= 0.f;
            unsigned long long bal2 = __ballot(sp2);
            if (sp2) v2 = 0.f;

            float h3 = 0.f;
            if (lane < N3) {
                unsigned long long m = bal2;
                while (m) {
                    int j = __builtin_ctzll(m);
                    m &= m - 1;
                    h3 += w3s[lane * N2 + j];
                }
            }
            v3 += (h3 - v3) * 0.5f;
            bool sp3 = (v3 - 1.0f) >= 0.f;
            if (lane < N3)
                out[(size_t)(t * BATCH + b) * N3 + lane] = sp3 ? 1.f : 0.f;
            if (sp3) v3 = 0.f;
        }
    }
}

extern "C" void kernel_launch(void* const* d_in, const int* in_sizes, int n_in,
                              void* d_out, int out_size, void* d_ws, size_t ws_size,
                              hipStream_t stream) {
    const float* x  = (const float*)d_in[0];   // [16,64,150,400] -> [1024][60000]
    const float* w1 = (const float*)d_in[1];   // [200][60000]
    const float* w2 = (const float*)d_in[2];   // [50][200]
    const float* w3 = (const float*)d_in[3];   // [2][50]
    float* out = (float*)d_out;                // [16][64][2]

    // ws layout: part bf16 [KSPLIT][1024][200], h1 f32
    const size_t h1_bytes  = (size_t)HN * 4;                 // 0.82 MB
    const size_t need125 = (size_t)125 * HN * 2 + h1_bytes;  // ~52 MB
    const bool big = ws_size >= need125;

    const int ksplit = big ? 125 : 25;
    unsigned short* part = (unsigned short*)d_ws;
    float* h1 = (float*)((char*)d_ws + (size_t)ksplit * HN * 2);

    if (big) {
        dim3 g(8, 125);
        gemm_lds<480, 15, 1000><<<g, 512, 0, stream>>>(x, w1, part);
        reduce_kernel<125><<<HN / 512, 256, 0, stream>>>(part, h1);
    } else {
        dim3 g(8, 25);
        gemm_lds<2400, 75, 200><<<g, 512, 0, stream>>>(x, w1, part);
        reduce_kernel<25><<<HN / 512, 256, 0, stream>>>(part, h1);
    }
    tail_kernel<<<BATCH, 256, 0, stream>>>(h1, w2, w3, out);
}